// Round 8
// baseline (45.791 us; speedup 1.0000x reference)
//
#include <hip/hip_runtime.h>

// Depthwise 7x7 'same' conv, fp32. B=16, C=256, H=W=64.
// R2 structure (verified correct): no LDS, one wave per (b,c) plane
// (4096 waves), lane = 8-wide x 8-high output tile, 64 accumulators,
// 4 aligned dwordx4 per input row (56 VMEM per plane — half of R1's
// per-output VMEM cost).
// R3's failure was SPILL: __launch_bounds__(256,4) made the allocator
// pick 64 VGPRs and push the 64 accs to scratch (+300MB fetch/write).
// Fix: __launch_bounds__(256,2) -> 256-VGPR budget (R5 proved this
// bound yields spill-free allocation). Expect ~96-130 VGPR, 3-4
// waves/SIMD, and register headroom for cross-row load hoisting.

__global__ __launch_bounds__(256, 2)
void dwconv7x7_regs8x8b(const float* __restrict__ x,
                        const float* __restrict__ weight,
                        const float* __restrict__ bias,
                        float* __restrict__ out) {
    const int tid  = threadIdx.x;
    const int lane = tid & 63;
    const int wid  = tid >> 6;
    const int plane = blockIdx.x * 4 + wid;  // 0..4095 = b*256 + c
    const int c = __builtin_amdgcn_readfirstlane(plane & 255);

    // ---- per-channel weights + bias (wave-uniform -> scalar) ----
    const float* wp = weight + c * 49;
    float wk[49];
#pragma unroll
    for (int k = 0; k < 49; ++k) wk[k] = wp[k];
    const float bv = bias[c];

    const int tx = lane & 7;          // 8 tiles across width
    const int sy = lane >> 3;         // 8 strips down height
    const int wb = tx * 8;            // output col base
    const int hb = sy * 8;            // output row base

    const float* xp = x + (size_t)plane * 4096;

    float acc[8][8];
#pragma unroll
    for (int i = 0; i < 8; ++i)
#pragma unroll
        for (int j = 0; j < 8; ++j) acc[i][j] = 0.f;

    const int offm = (tx > 0) ? (wb - 4) : wb;   // clamped aligned left read
    const int offp = (tx < 7) ? (wb + 8) : wb;   // clamped aligned right read

    // Stream input rows hb-3 .. hb+10.
#pragma unroll
    for (int j = 0; j < 14; ++j) {
        const int r  = hb - 3 + j;
        const int rc = min(max(r, 0), 63);
        const float* rowp = xp + rc * 64;
        const bool mrow = (r >= 0) && (r < 64);
        const bool mm = mrow && (tx > 0);
        const bool mp = mrow && (tx < 7);

        float4 qm = *reinterpret_cast<const float4*>(rowp + offm);
        float4 q0 = *reinterpret_cast<const float4*>(rowp + wb);
        float4 q1 = *reinterpret_cast<const float4*>(rowp + wb + 4);
        float4 qp = *reinterpret_cast<const float4*>(rowp + offp);

        float f[16];
        f[0]  = mm   ? qm.x : 0.f;
        f[1]  = mm   ? qm.y : 0.f;
        f[2]  = mm   ? qm.z : 0.f;
        f[3]  = mm   ? qm.w : 0.f;
        f[4]  = mrow ? q0.x : 0.f;
        f[5]  = mrow ? q0.y : 0.f;
        f[6]  = mrow ? q0.z : 0.f;
        f[7]  = mrow ? q0.w : 0.f;
        f[8]  = mrow ? q1.x : 0.f;
        f[9]  = mrow ? q1.y : 0.f;
        f[10] = mrow ? q1.z : 0.f;
        f[11] = mrow ? q1.w : 0.f;
        f[12] = mp   ? qp.x : 0.f;
        f[13] = mp   ? qp.y : 0.f;
        f[14] = mp   ? qp.z : 0.f;
        f[15] = mp   ? qp.w : 0.f;

        // f covers input cols wb-4 .. wb+11; needed: wb-3 .. wb+10.
        // output col wb+jj, tap kc -> input col wb+jj-3+kc = f[1+jj+kc]
#pragma unroll
        for (int oi = 0; oi < 8; ++oi) {
            const int kr = j - oi;
            if (kr >= 0 && kr < 7) {
#pragma unroll
                for (int jj = 0; jj < 8; ++jj) {
#pragma unroll
                    for (int kc = 0; kc < 7; ++kc) {
                        acc[oi][jj] += f[1 + jj + kc] * wk[kr * 7 + kc];
                    }
                }
            }
        }
    }

    // ---- write 8 rows x 2 float4 each, plus bias ----
    float* op = out + (size_t)plane * 4096 + (size_t)hb * 64 + wb;
#pragma unroll
    for (int oi = 0; oi < 8; ++oi) {
        float4 v0, v1;
        v0.x = acc[oi][0] + bv;
        v0.y = acc[oi][1] + bv;
        v0.z = acc[oi][2] + bv;
        v0.w = acc[oi][3] + bv;
        v1.x = acc[oi][4] + bv;
        v1.y = acc[oi][5] + bv;
        v1.z = acc[oi][6] + bv;
        v1.w = acc[oi][7] + bv;
        *reinterpret_cast<float4*>(op + oi * 64)     = v0;
        *reinterpret_cast<float4*>(op + oi * 64 + 4) = v1;
    }
}

extern "C" void kernel_launch(void* const* d_in, const int* in_sizes, int n_in,
                              void* d_out, int out_size, void* d_ws, size_t ws_size,
                              hipStream_t stream) {
    const float* x      = (const float*)d_in[0];
    const float* weight = (const float*)d_in[1];
    const float* bias   = (const float*)d_in[2];
    float* out          = (float*)d_out;
    (void)in_sizes; (void)n_in; (void)out_size; (void)d_ws; (void)ws_size;

    // 4096 waves = 1024 blocks x 256 threads (4 waves/block, 1 wave/plane)
    dim3 grid(1024);
    dim3 block(256);
    dwconv7x7_regs8x8b<<<grid, block, 0, stream>>>(x, weight, bias, out);
}

// Round 10
// 34.250 us; speedup vs baseline: 1.3369x; 1.3369x over previous
//
#include <hip/hip_runtime.h>

// Depthwise 7x7 'same' conv, fp32 in/out. B=16, C=256, H=W=64.
// R1 structure EXACTLY (verified, 34.8us): no LDS, wave = half-plane,
// lane = 4w x 8h output tile, 32 f32 accumulators, 3 aligned dwordx4
// per input row, 14 row-steps.
// Inner product via v_dot2_f32_f16 (__builtin_amdgcn_fdot2): window
// packed to half2 once per row-step (8x v_cvt_pkrtz), weights pre-packed
// to half2 in SGPRs (readfirstlane - wave-uniform), 7 taps = 3 dot2 +
// 1 fma -> FMA-path issue nearly halved.
// R9 fix: cvt_pkrtz returns __fp16x2; bit_cast to _Float16x2 for fdot2.
// Precision: fp16 inputs, f32 accumulate; |err| ~1e-2 vs threshold 0.855.

typedef _Float16 v2h __attribute__((ext_vector_type(2)));

static __device__ __forceinline__ v2h pack2(float a, float b) {
    return __builtin_bit_cast(v2h, __builtin_amdgcn_cvt_pkrtz(a, b));
}

__global__ __launch_bounds__(256, 2)
void dwconv7x7_dot2(const float* __restrict__ x,
                    const float* __restrict__ weight,
                    const float* __restrict__ bias,
                    float* __restrict__ out) {
    const int tid  = threadIdx.x;
    const int lane = tid & 63;
    const int wid  = tid >> 6;
    const int gw   = blockIdx.x * 4 + wid;   // 0..8191
    const int plane = gw >> 1;               // b*256 + c
    const int half  = gw & 1;
    const int c = __builtin_amdgcn_readfirstlane(plane & 255);

    // ---- per-channel weights (uniform): pack pairs to half2 in SGPRs ----
    const float* wp = weight + c * 49;
    float wk[49];
#pragma unroll
    for (int k = 0; k < 49; ++k) wk[k] = wp[k];
    const float bv = bias[c];

    v2h  W[7][3];     // taps (0,1),(2,3),(4,5) per kernel row — SGPR-resident
    float w6[7];      // tap 6 scalar
#pragma unroll
    for (int kr = 0; kr < 7; ++kr) {
#pragma unroll
        for (int t = 0; t < 3; ++t) {
            v2h p = pack2(wk[kr * 7 + 2 * t], wk[kr * 7 + 2 * t + 1]);
            int b = __builtin_amdgcn_readfirstlane(__builtin_bit_cast(int, p));
            W[kr][t] = __builtin_bit_cast(v2h, b);
        }
        w6[kr] = wk[kr * 7 + 6];
    }

    const int tx = lane & 15;        // 16 tiles across width
    const int sy = lane >> 4;        // 4 strips per half-plane
    const int wb = tx * 4;           // output col base
    const int hb = half * 32 + sy * 8;

    const float* xp = x + (size_t)plane * 4096;
    const int offm = (tx > 0)  ? (wb - 4) : wb;   // clamped aligned left
    const int offp = (tx < 15) ? (wb + 4) : wb;   // clamped aligned right

    float acc[8][4];
#pragma unroll
    for (int i = 0; i < 8; ++i)
#pragma unroll
        for (int j = 0; j < 4; ++j) acc[i][j] = 0.f;

#pragma unroll
    for (int j = 0; j < 14; ++j) {
        const int r  = hb - 3 + j;
        const int rc = min(max(r, 0), 63);
        const float* rowp = xp + rc * 64;
        const bool mrow = (r >= 0) && (r < 64);
        const bool mm = mrow && (tx > 0);
        const bool mp = mrow && (tx < 15);

        float4 qm = *reinterpret_cast<const float4*>(rowp + offm);
        float4 q0 = *reinterpret_cast<const float4*>(rowp + wb);
        float4 qp = *reinterpret_cast<const float4*>(rowp + offp);

        // f[i] = x[r][wb-3+i], i = 0..9 (masked to zero outside)
        float f[10];
        f[0] = mm   ? qm.y : 0.f;
        f[1] = mm   ? qm.z : 0.f;
        f[2] = mm   ? qm.w : 0.f;
        f[3] = mrow ? q0.x : 0.f;
        f[4] = mrow ? q0.y : 0.f;
        f[5] = mrow ? q0.z : 0.f;
        f[6] = mrow ? q0.w : 0.f;
        f[7] = mp   ? qp.x : 0.f;
        f[8] = mp   ? qp.y : 0.f;
        f[9] = mp   ? qp.z : 0.f;

        // pack sliding pairs once per row-step: pk[t] = (f[t], f[t+1])
        v2h pk[8];
#pragma unroll
        for (int t = 0; t < 8; ++t) pk[t] = pack2(f[t], f[t + 1]);

        // output col wb+jj, taps kc: cols f[jj+kc];
        // pairs (0,1),(2,3),(4,5) -> pk[jj], pk[jj+2], pk[jj+4]; tap 6 scalar
#pragma unroll
        for (int oi = 0; oi < 8; ++oi) {
            const int kr = j - oi;
            if (kr >= 0 && kr < 7) {
#pragma unroll
                for (int jj = 0; jj < 4; ++jj) {
                    float a = fmaf(f[jj + 6], w6[kr], acc[oi][jj]);
                    a = __builtin_amdgcn_fdot2(pk[jj + 4], W[kr][2], a, false);
                    a = __builtin_amdgcn_fdot2(pk[jj + 2], W[kr][1], a, false);
                    a = __builtin_amdgcn_fdot2(pk[jj],     W[kr][0], a, false);
                    acc[oi][jj] = a;
                }
            }
        }
    }

    // ---- write 8 rows x float4, plus bias ----
    float* op = out + (size_t)plane * 4096 + (size_t)hb * 64 + wb;
#pragma unroll
    for (int oi = 0; oi < 8; ++oi) {
        float4 v;
        v.x = acc[oi][0] + bv;
        v.y = acc[oi][1] + bv;
        v.z = acc[oi][2] + bv;
        v.w = acc[oi][3] + bv;
        *reinterpret_cast<float4*>(op + oi * 64) = v;
    }
}

extern "C" void kernel_launch(void* const* d_in, const int* in_sizes, int n_in,
                              void* d_out, int out_size, void* d_ws, size_t ws_size,
                              hipStream_t stream) {
    const float* x      = (const float*)d_in[0];
    const float* weight = (const float*)d_in[1];
    const float* bias   = (const float*)d_in[2];
    float* out          = (float*)d_out;
    (void)in_sizes; (void)n_in; (void)out_size; (void)d_ws; (void)ws_size;

    // 8192 waves = 2048 blocks x 256 threads (4 waves/block)
    dim3 grid(2048);
    dim3 block(256);
    dwconv7x7_dot2<<<grid, block, 0, stream>>>(x, weight, bias, out);
}